// Round 1
// baseline (17062.265 us; speedup 1.0000x reference)
//
#include <hip/hip_runtime.h>
#include <math.h>

#define D_DIM 2048
#define B_DIM 32
#define T_DIM 512
#define BD    65536            // B*D
#define OFF_LOG  33554432      // T*B*D
#define OFF_SIGN 67174400      // OFF_LOG + (T+1)*B*D
#define OFF_HLIN 100794368     // OFF_SIGN + (T+1)*B*D

// ======================= Phase A: spectral norm =======================

__global__ void k_init_u(float* __restrict__ u){
  __shared__ float red[256];
  int tid = threadIdx.x;
  float vals[8]; float s = 0.f;
  #pragma unroll
  for (int r = 0; r < 8; ++r){
    int i = tid + 256*r;
    float c = cosf((float)i * 0.7f + 0.3f);
    vals[r] = c; s += c*c;
  }
  red[tid] = s; __syncthreads();
  for (int st = 128; st > 0; st >>= 1){
    if (tid < st) red[tid] += red[tid+st];
    __syncthreads();
  }
  float nrm = sqrtf(red[0]);
  #pragma unroll
  for (int r = 0; r < 8; ++r){
    int i = tid + 256*r;
    u[i] = vals[r] / nrm;
  }
}

// out[j] = sum_i W[i][j] * u[i]   (W^T @ u), 2048 threads
__global__ __launch_bounds__(256) void k_matvec_T(const float* __restrict__ W,
                                                  const float* __restrict__ u,
                                                  float* __restrict__ out){
  int j = blockIdx.x * 256 + threadIdx.x;
  float acc = 0.f;
  for (int i = 0; i < D_DIM; ++i)
    acc = fmaf(W[(size_t)i * D_DIM + j], u[i], acc);
  out[j] = acc;
}

// out[i] = sum_j W[i][j] * v[j]   (W @ v), one wave per row
__global__ __launch_bounds__(64) void k_matvec_row(const float* __restrict__ W,
                                                   const float* __restrict__ v,
                                                   float* __restrict__ out){
  int i = blockIdx.x;
  int lane = threadIdx.x;
  float acc = 0.f;
  #pragma unroll 4
  for (int s = 0; s < 32; ++s){
    int j = lane + 64*s;
    acc = fmaf(W[(size_t)i * D_DIM + j], v[j], acc);
  }
  #pragma unroll
  for (int off = 32; off > 0; off >>= 1)
    acc += __shfl_down(acc, off, 64);
  if (lane == 0) out[i] = acc;
}

__global__ void k_normalize(const float* __restrict__ src, float* __restrict__ dst, float eps){
  __shared__ float red[256];
  int tid = threadIdx.x;
  float s = 0.f;
  #pragma unroll
  for (int r = 0; r < 8; ++r){ float xv = src[tid + 256*r]; s += xv*xv; }
  red[tid] = s; __syncthreads();
  for (int st = 128; st > 0; st >>= 1){
    if (tid < st) red[tid] += red[tid+st];
    __syncthreads();
  }
  float nrm = sqrtf(red[0]) + eps;
  #pragma unroll
  for (int r = 0; r < 8; ++r){ int i = tid + 256*r; dst[i] = src[i] / nrm; }
}

// sigma = |u . (W v)| where wv = W@v (the last un-normalized u); scale = 0.9/(sigma+1e-8)
__global__ void k_sigma_scale(const float* __restrict__ u, const float* __restrict__ wv,
                              float* __restrict__ scale){
  __shared__ float red[256];
  int tid = threadIdx.x;
  float s = 0.f;
  #pragma unroll
  for (int r = 0; r < 8; ++r){ int i = tid + 256*r; s += u[i]*wv[i]; }
  red[tid] = s; __syncthreads();
  for (int st = 128; st > 0; st >>= 1){
    if (tid < st) red[tid] += red[tid+st];
    __syncthreads();
  }
  if (tid == 0) scale[0] = 0.9f / (fabsf(red[0]) + 1e-8f);
}

// Rt[k][d] = Rh[d][k] * scale  (transposed + scaled R_h_eff)
__global__ __launch_bounds__(256) void k_transpose_scale(const float* __restrict__ Rh,
                                                         const float* __restrict__ scale,
                                                         float* __restrict__ Rt){
  __shared__ float tile[32][33];
  int tx = threadIdx.x & 31, ty = threadIdx.x >> 5;   // 32 x 8
  int d0 = blockIdx.x * 32, k0 = blockIdx.y * 32;
  float s = scale[0];
  #pragma unroll
  for (int r = 0; r < 4; ++r){
    int dd = ty + 8*r;
    tile[dd][tx] = Rh[(size_t)(d0 + dd) * D_DIM + k0 + tx];
  }
  __syncthreads();
  #pragma unroll
  for (int r = 0; r < 4; ++r){
    int kk = ty + 8*r;
    Rt[(size_t)(k0 + kk) * D_DIM + d0 + tx] = tile[tx][kk] * s;
  }
}

// h0 = sign_h0 * exp(log_h0); also emit log_h[0], sign_h[0]
__global__ __launch_bounds__(256) void k_init_h(const float* __restrict__ log_h0,
                                                const float* __restrict__ sign_h0,
                                                float* __restrict__ h_bd,
                                                float* __restrict__ h_db,
                                                float* out){
  int flat = blockIdx.x * 256 + threadIdx.x;   // 0..65535
  int d = flat & 2047, b = flat >> 11;
  float l = log_h0[flat], sg = sign_h0[flat];
  float h = sg * expf(l);
  h_bd[flat] = h;
  h_db[d * 32 + b] = h;
  out[OFF_LOG  + flat] = l;
  out[OFF_SIGN + flat] = sg;
}

// ======================= Phase B: dual GEMM (C = A @ B^T + bias) =======================
// A: M x K (x flattened), B1/B2: N x K row-major. C1 = pre_v, C2 = pre_delta.
#define BM 64
#define BN 64
#define BK 32

__global__ __launch_bounds__(256) void gemm_dual(const float* __restrict__ A,
    const float* __restrict__ B1, const float* __restrict__ B2,
    const float* __restrict__ bias1, const float* __restrict__ bias2,
    float* C1, float* C2){
  const int K = D_DIM, N = D_DIM;
  __shared__ __align__(16) float As [BK][BM+4];
  __shared__ __align__(16) float Bs1[BK][BN+4];
  __shared__ __align__(16) float Bs2[BK][BN+4];
  int tid = threadIdx.x;
  int m0 = blockIdx.y * BM, n0 = blockIdx.x * BN;
  int tx = tid & 15, ty = tid >> 4;
  int lrow = tid >> 3;          // 0..31
  int lcol = (tid & 7) * 4;     // 0..28
  float acc1[4][4] = {{0.f}}, acc2[4][4] = {{0.f}};

  for (int kt = 0; kt < K; kt += BK){
    #pragma unroll
    for (int h = 0; h < 2; ++h){
      int r = lrow + 32*h;
      float4 av = *(const float4*)&A [(size_t)(m0 + r) * K + kt + lcol];
      As [lcol+0][r] = av.x; As [lcol+1][r] = av.y; As [lcol+2][r] = av.z; As [lcol+3][r] = av.w;
      float4 bv = *(const float4*)&B1[(size_t)(n0 + r) * K + kt + lcol];
      Bs1[lcol+0][r] = bv.x; Bs1[lcol+1][r] = bv.y; Bs1[lcol+2][r] = bv.z; Bs1[lcol+3][r] = bv.w;
      float4 cv = *(const float4*)&B2[(size_t)(n0 + r) * K + kt + lcol];
      Bs2[lcol+0][r] = cv.x; Bs2[lcol+1][r] = cv.y; Bs2[lcol+2][r] = cv.z; Bs2[lcol+3][r] = cv.w;
    }
    __syncthreads();
    #pragma unroll 8
    for (int k = 0; k < BK; ++k){
      float4 a4  = *(const float4*)&As [k][ty*4];
      float4 b14 = *(const float4*)&Bs1[k][tx*4];
      float4 b24 = *(const float4*)&Bs2[k][tx*4];
      float av[4]  = {a4.x,  a4.y,  a4.z,  a4.w};
      float b1v[4] = {b14.x, b14.y, b14.z, b14.w};
      float b2v[4] = {b24.x, b24.y, b24.z, b24.w};
      #pragma unroll
      for (int i = 0; i < 4; ++i)
        #pragma unroll
        for (int j = 0; j < 4; ++j){
          acc1[i][j] = fmaf(av[i], b1v[j], acc1[i][j]);
          acc2[i][j] = fmaf(av[i], b2v[j], acc2[i][j]);
        }
    }
    __syncthreads();
  }
  float4 bb1 = *(const float4*)&bias1[n0 + tx*4];
  float4 bb2 = *(const float4*)&bias2[n0 + tx*4];
  float bb1a[4] = {bb1.x, bb1.y, bb1.z, bb1.w};
  float bb2a[4] = {bb2.x, bb2.y, bb2.z, bb2.w};
  #pragma unroll
  for (int i = 0; i < 4; ++i){
    float4 o1, o2;
    o1.x = acc1[i][0] + bb1a[0]; o1.y = acc1[i][1] + bb1a[1];
    o1.z = acc1[i][2] + bb1a[2]; o1.w = acc1[i][3] + bb1a[3];
    o2.x = acc2[i][0] + bb2a[0]; o2.y = acc2[i][1] + bb2a[1];
    o2.z = acc2[i][2] + bb2a[2]; o2.w = acc2[i][3] + bb2a[3];
    size_t row = (size_t)(m0 + ty*4 + i) * N + n0 + tx*4;
    *(float4*)&C1[row] = o1;
    *(float4*)&C2[row] = o2;
  }
}

// ======================= Phase C: recurrence =======================
// matvec: partial[kb][b][d] = sum_{k in slice} h_db[k][b] * Rt[k][d]
// grid 256 blocks (dtile = bx&31 -> XCD-affine, kb = bx>>5), 512 threads (8 waves)
__global__ __launch_bounds__(512) void step_matvec(const float* __restrict__ Rt,
                                                   const float* __restrict__ h_db,
                                                   float* __restrict__ partial){
  int bx = blockIdx.x;
  int dtile = bx & 31, kb = bx >> 5;
  int tid = threadIdx.x;
  int lane = tid & 63, w = tid >> 6;        // wave 0..7
  int d = dtile * 64 + lane;
  int k0 = (kb * 8 + w) * 32;
  float acc[32];
  #pragma unroll
  for (int b = 0; b < 32; ++b) acc[b] = 0.f;

  #pragma unroll 2
  for (int k = k0; k < k0 + 32; ++k){
    float r = Rt[(size_t)k * D_DIM + d];
    const float4* hv = (const float4*)&h_db[k * 32];
    #pragma unroll
    for (int b4 = 0; b4 < 8; ++b4){
      float4 h4 = hv[b4];
      acc[b4*4+0] = fmaf(r, h4.x, acc[b4*4+0]);
      acc[b4*4+1] = fmaf(r, h4.y, acc[b4*4+1]);
      acc[b4*4+2] = fmaf(r, h4.z, acc[b4*4+2]);
      acc[b4*4+3] = fmaf(r, h4.w, acc[b4*4+3]);
    }
  }

  // reduce 8 waves -> 1 via 4-region LDS (32 KB)
  __shared__ float red[4][32][64];
  if (w < 4){
    #pragma unroll
    for (int b = 0; b < 32; ++b) red[w][b][lane] = acc[b];
  }
  __syncthreads();
  if (w >= 4){
    #pragma unroll
    for (int b = 0; b < 32; ++b) red[w-4][b][lane] += acc[b];
  }
  __syncthreads();
  // 512 threads each sum one float4 group over 4 regions
  int g = tid;
  int b = g >> 4;             // (g*4)/64
  int dl4 = (g & 15) * 4;
  float4 s0 = *(const float4*)&red[0][b][dl4];
  float4 s1 = *(const float4*)&red[1][b][dl4];
  float4 s2 = *(const float4*)&red[2][b][dl4];
  float4 s3 = *(const float4*)&red[3][b][dl4];
  float4 s;
  s.x = (s0.x + s1.x) + (s2.x + s3.x);
  s.y = (s0.y + s1.y) + (s2.y + s3.y);
  s.z = (s0.z + s1.z) + (s2.z + s3.z);
  s.w = (s0.w + s1.w) + (s2.w + s3.w);
  *(float4*)&partial[(size_t)kb * BD + b * D_DIM + dtile * 64 + dl4] = s;
}

// elementwise: h_t from hdot(t) and h(t-1); writes all outputs for step t
__global__ __launch_bounds__(256) void step_elem(int t,
    const float* __restrict__ partial, const float* __restrict__ x,
    const float* __restrict__ b_gate,
    float* __restrict__ h_bd, float* __restrict__ h_db,
    float* out){
  int flat = blockIdx.x * 256 + threadIdx.x;     // 0..65535
  int d = flat & 2047, b = flat >> 11;
  size_t off = (size_t)t * BD + flat;
  const float* pre_v = out;                 // aliases output slot
  const float* pre_d = out + OFF_HLIN;      // aliases h_linear slot

  float hdot = 0.f;
  #pragma unroll
  for (int kb = 0; kb < 8; ++kb) hdot += partial[(size_t)kb * BD + flat];

  float v = pre_v[off] + hdot;
  float cand = tanhf(v);
  float pd = pre_d[off];
  float delta = 1.f / (1.f + expf(-pd));
  float hp = h_bd[flat];
  float h = (1.f - delta) * hp + delta * cand;

  float zg = h + x[off] + b_gate[d];
  float gate = zg / (1.f + expf(-zg));      // silu
  out[off] = h * gate;                      // output[t]
  out[OFF_HLIN + off] = h;                  // h_linear[t]
  size_t off2 = (size_t)(t + 1) * BD + flat;
  out[OFF_LOG  + off2] = logf(fmaxf(fabsf(h), 1e-30f));
  out[OFF_SIGN + off2] = (h >= 0.f) ? 1.f : -1.f;
  h_bd[flat] = h;
  h_db[d * 32 + b] = h;
}

// ======================= launch =======================
extern "C" void kernel_launch(void* const* d_in, const int* in_sizes, int n_in,
                              void* d_out, int out_size, void* d_ws, size_t ws_size,
                              hipStream_t stream){
  const float* x       = (const float*)d_in[0];
  const float* log_h0  = (const float*)d_in[1];
  const float* sign_h0 = (const float*)d_in[2];
  const float* R_h     = (const float*)d_in[3];
  const float* R_x     = (const float*)d_in[4];
  const float* W_d     = (const float*)d_in[5];
  const float* bb      = (const float*)d_in[6];
  const float* b_delta = (const float*)d_in[7];
  const float* b_gate  = (const float*)d_in[8];
  float* out = (float*)d_out;
  float* ws  = (float*)d_ws;

  float* Rt      = ws;                       // 4M floats (16 MB)
  float* partial = ws + 4194304;             // 8*65536
  float* h_bd    = partial + 524288;
  float* h_db    = h_bd + BD;
  float* u       = h_db + BD;
  float* uraw    = u + 2048;
  float* vv      = uraw + 2048;
  float* tmp     = vv + 2048;
  float* scale   = tmp + 2048;

  // Phase A: spectral norm of R_h -> Rt (transposed, scaled)
  k_init_u<<<1, 256, 0, stream>>>(u);
  for (int it = 0; it < 3; ++it){
    k_matvec_T  <<<8, 256, 0, stream>>>(R_h, u, tmp);
    k_normalize <<<1, 256, 0, stream>>>(tmp, vv, 1e-8f);
    k_matvec_row<<<2048, 64, 0, stream>>>(R_h, vv, uraw);
    k_normalize <<<1, 256, 0, stream>>>(uraw, u, 1e-8f);
  }
  k_sigma_scale<<<1, 256, 0, stream>>>(u, uraw, scale);
  k_transpose_scale<<<dim3(64, 64), 256, 0, stream>>>(R_h, scale, Rt);
  k_init_h<<<256, 256, 0, stream>>>(log_h0, sign_h0, h_bd, h_db, out);

  // Phase B: pre_v -> output slot, pre_delta -> h_linear slot
  gemm_dual<<<dim3(32, 256), 256, 0, stream>>>(x, R_x, W_d, bb, b_delta,
                                               out, out + OFF_HLIN);

  // Phase C: 512 sequential steps
  for (int t = 0; t < T_DIM; ++t){
    step_matvec<<<256, 512, 0, stream>>>(Rt, h_db, partial);
    step_elem  <<<256, 256, 0, stream>>>(t, partial, x, b_gate, h_bd, h_db, out);
  }
}